// Round 17
// baseline (517.110 us; speedup 1.0000x reference)
//
#include <hip/hip_runtime.h>
#include <hip/hip_bf16.h>

#define N_TOK 16384
#define DDIM  512
#define HDIM  1024
#define ODIM  512
#define NG    3
#define NE    4
#define NGE   12
#define TASK_CAP 272

typedef __bf16 bf16x8 __attribute__((ext_vector_type(8)));
typedef float  f32x4  __attribute__((ext_vector_type(4)));
typedef unsigned int u32;

// async global->LDS, 16B per lane, lane l lands at ldst + l*16 (wave-uniform dest)
__device__ __forceinline__ void gld_lds16(const void* gsrc, void* ldst) {
    __builtin_amdgcn_global_load_lds(
        (const __attribute__((address_space(1))) u32*)gsrc,
        (__attribute__((address_space(3))) u32*)ldst, 16, 0, 0);
}

// ---------------- workspace layout (bytes) ----------------
static constexpr size_t OFF_WSLOT = 512;                               // N*2 floats
static constexpr size_t OFF_ELIST = OFF_WSLOT + (size_t)N_TOK*2*4;     // 12*N ints
static constexpr size_t OFF_TASK  = 917504;                            // int2[TASK_CAP]
static constexpr size_t OFF_XBF   = 1048576;                           // N*D bf16
static constexpr size_t OFF_W1    = OFF_XBF + (size_t)N_TOK*DDIM*2;
static constexpr size_t OFF_W2    = OFF_W1  + (size_t)NGE*HDIM*DDIM*2;
static constexpr size_t OFF_WP    = OFF_W2  + (size_t)NGE*HDIM*HDIM*2;
static constexpr size_t OFF_W3    = OFF_WP  + (size_t)NGE*HDIM*DDIM*2;
static constexpr size_t OFF_H1    = OFF_W3  + (size_t)NGE*ODIM*HDIM*2;
static constexpr size_t OFF_U     = OFF_H1  + (size_t)N_TOK*2*HDIM*2;
static constexpr size_t OFF_Y     = OFF_U   + (size_t)N_TOK*2*HDIM*2;
static constexpr size_t WS_NEED   = OFF_Y   + (size_t)N_TOK*2*ODIM*2;

// ---------------- fused prep: blocks [0,256) route, rest cast fp32->bf16 ----------------
__global__ __launch_bounds__(256) void prep_k(
        const float* __restrict__ x,  const float* __restrict__ Wm,
        const float* __restrict__ bm, const float* __restrict__ Wr,
        const float* __restrict__ br,
        const float* __restrict__ w1, const float* __restrict__ w2,
        const float* __restrict__ wp, const float* __restrict__ w3,
        __bf16* xbf, __bf16* w1b, __bf16* w2b, __bf16* wpb, __bf16* w3b,
        float* pmsum, float* psum, int* cnt, int* ecount,
        int* elist, float* wslot) {
    __shared__ float lpm[NG];
    __shared__ float lpsum[NGE];
    __shared__ int   lcnt[NG];
    __shared__ int   lec[NGE];
    __shared__ int   lbase[NGE];
    __shared__ int   lentry[NGE][64];

    int tid = threadIdx.x;

    if (blockIdx.x >= 256) {
        // ---------- cast path ----------
        int cbid = blockIdx.x - 256;
        int ctid = cbid * 256 + tid;
        int stride = (gridDim.x - 256) * 256;
        auto seg = [&](const float* __restrict__ s, __bf16* __restrict__ d, int n4) {
            const float4* s4 = (const float4*)s;
            uint2* d4 = (uint2*)d;
            for (int i = ctid; i < n4; i += stride) {
                float4 v = s4[i];
                union { __bf16 h[4]; uint2 u; } o;
                o.h[0] = (__bf16)v.x; o.h[1] = (__bf16)v.y;
                o.h[2] = (__bf16)v.z; o.h[3] = (__bf16)v.w;
                d4[i] = o.u;
            }
        };
        seg(x,  xbf, N_TOK*DDIM/4);
        seg(w1, w1b, NGE*HDIM*DDIM/4);
        seg(w2, w2b, NGE*HDIM*HDIM/4);
        seg(wp, wpb, NGE*HDIM*DDIM/4);
        seg(w3, w3b, NGE*ODIM*HDIM/4);
        return;
    }

    // ---------- routing path (block-aggregated atomics) ----------
    if (tid < NG)  { lpm[tid] = 0.f; lcnt[tid] = 0; }
    if (tid < NGE) { lpsum[tid] = 0.f; lec[tid] = 0; }
    __syncthreads();

    int wid = tid >> 6, lane = tid & 63;

    #pragma unroll 1
    for (int i = 0; i < 16; ++i) {
        int t = blockIdx.x * 64 + i * 4 + wid;

        const float4* xr = (const float4*)(x + (size_t)t * DDIM);
        float4 xa = xr[lane*2], xb = xr[lane*2+1];

        float meta[NG];
        #pragma unroll
        for (int gi = 0; gi < NG; ++gi) {
            const float4* w = (const float4*)(Wm + gi*DDIM);
            float4 wa = w[lane*2], wb = w[lane*2+1];
            float s = xa.x*wa.x + xa.y*wa.y + xa.z*wa.z + xa.w*wa.w
                    + xb.x*wb.x + xb.y*wb.y + xb.z*wb.z + xb.w*wb.w;
            #pragma unroll
            for (int off = 32; off > 0; off >>= 1) s += __shfl_xor(s, off);
            meta[gi] = s + bm[gi];
        }
        int g = 0;
        if (meta[1] > meta[g]) g = 1;
        if (meta[2] > meta[g]) g = 2;

        float mm = fmaxf(meta[0], fmaxf(meta[1], meta[2]));
        float e0 = expf(meta[0]-mm), e1 = expf(meta[1]-mm), e2 = expf(meta[2]-mm);
        float inv = 1.f / (e0 + e1 + e2);

        float sel[NE];
        #pragma unroll
        for (int e = 0; e < NE; ++e) {
            const float4* w = (const float4*)(Wr + (size_t)(g*NE + e)*DDIM);
            float4 wa = w[lane*2], wb = w[lane*2+1];
            float s = xa.x*wa.x + xa.y*wa.y + xa.z*wa.z + xa.w*wa.w
                    + xb.x*wb.x + xb.y*wb.y + xb.z*wb.z + xb.w*wb.w;
            #pragma unroll
            for (int off = 32; off > 0; off >>= 1) s += __shfl_xor(s, off);
            sel[e] = s + br[g*NE + e];
        }
        float ms = fmaxf(fmaxf(sel[0],sel[1]), fmaxf(sel[2],sel[3]));
        float pe[NE]; float ss = 0.f;
        #pragma unroll
        for (int e = 0; e < NE; ++e) { pe[e] = expf(sel[e]-ms); ss += pe[e]; }
        float invs = 1.f / ss;

        int i0 = 0;
        #pragma unroll
        for (int e = 1; e < NE; ++e) if (sel[e] > sel[i0]) i0 = e;
        int i1 = (i0 == 0) ? 1 : 0;
        #pragma unroll
        for (int e = 0; e < NE; ++e) if (e != i0 && sel[e] > sel[i1]) i1 = e;
        float ew = expf(sel[i1] - sel[i0]);
        float wden = 1.f / (1.f + ew);

        if (lane == 0) {
            atomicAdd(&lpm[0], e0*inv);
            atomicAdd(&lpm[1], e1*inv);
            atomicAdd(&lpm[2], e2*inv);
            #pragma unroll
            for (int e = 0; e < NE; ++e) atomicAdd(&lpsum[g*NE + e], pe[e]*invs);
            atomicAdd(&lcnt[g], 1);
            int ee0 = g*NE + i0, ee1 = g*NE + i1;
            int p0 = atomicAdd(&lec[ee0], 1);
            lentry[ee0][p0] = t*2;
            int p1 = atomicAdd(&lec[ee1], 1);
            lentry[ee1][p1] = t*2 + 1;
            wslot[t*2]   = wden;
            wslot[t*2+1] = ew * wden;
        }
    }
    __syncthreads();

    if (tid < NG)  { atomicAdd(pmsum + tid, lpm[tid]); atomicAdd(cnt + tid, lcnt[tid]); }
    if (tid < NGE) { atomicAdd(psum + tid, lpsum[tid]);
                     lbase[tid] = atomicAdd(ecount + tid, lec[tid]); }
    __syncthreads();

    for (int e = wid; e < NGE; e += 4) {
        int c = lec[e], base = lbase[e];
        for (int j = lane; j < c; j += 64)
            elist[e*N_TOK + base + j] = lentry[e][j];
    }
}

// ---------------- aux scalar + GEMM task list (BM=128 tiles) ----------------
__global__ void finalize_aux_k(const float* pmsum, const float* psum, const int* cnt,
                               const int* ecount, int2* tasks, int* ntasks,
                               float* outAux) {
    if (threadIdx.x != 0 || blockIdx.x != 0) return;
    float s = 0.f;
    for (int i = 0; i < NG; ++i) { float p = pmsum[i] / (float)N_TOK; s += p*p; }
    float aux = 0.01f * NG * s;
    for (int gg = 0; gg < NG; ++gg) {
        int c = cnt[gg];
        if (c > 0) {
            float s2 = 0.f;
            for (int e = 0; e < NE; ++e) { float m = psum[gg*NE+e] / (float)c; s2 += m*m; }
            aux += 0.01f * NE * s2;
        }
    }
    *outAux = aux;
    int nt = 0;
    for (int ge = 0; ge < NGE; ++ge) {
        int c = ecount[ge];
        for (int m0 = 0; m0 < c; m0 += 128) tasks[nt++] = make_int2(ge, m0);
    }
    *ntasks = nt;
}

// ---------------- grouped GEMM: 128xBN, BK=32 triple-buffer, counted vmcnt ----------
// Proven r12/r14 schedule, generalized over BN. BN=256 (stage-2): the A-tile
// is SHARED across a 256-col output panel -> 32 MFMA per barrier (vs 16),
// ds_read:MFMA = 12:32 (vs 8:16), half the blocks for the heaviest kernel.
// LDS 72 KB -> 2 blocks/CU. BN=128 instantiations byte-identical to r14.
// Chunked-bijective task->XCD map keeps weights L2-resident per XCD.
template<int NDIM, int BN, bool RELU, bool TWOPASS>
__global__ __launch_bounds__(256) void expert_gemm_k(
        const __bf16* __restrict__ A1, int shift1, int k1, const __bf16* __restrict__ B1,
        const __bf16* __restrict__ A2, int shift2, int k2, const __bf16* __restrict__ B2,
        const float* __restrict__ bias1, const float* __restrict__ bias2,
        __bf16* __restrict__ Out,
        const int* __restrict__ ecount, const int* __restrict__ elist,
        const int2* __restrict__ tasks, const int* __restrict__ ntasks) {
    constexpr int NPAN = NDIM / BN;             // panels (power of two)
    constexpr int PSH  = (NPAN == 8) ? 3 : ((NPAN == 4) ? 2 : 1);
    constexpr int NFR  = BN / 32;               // N-frags per wave
    constexpr int BCH  = BN / 64;               // B staging chunks (16 rows) per wave
    int T = *ntasks;
    int q = T >> 3, r = T & 7;
    int xcd  = blockIdx.x & 7;
    int idx  = blockIdx.x >> 3;                 // local block index on this XCD
    int tloc = idx >> PSH;                      // local task
    int panel = idx & (NPAN - 1);
    int cx = q + (xcd < r ? 1 : 0);
    if (tloc >= cx) return;
    int task = (xcd < r ? xcd * (q + 1) : r * (q + 1) + (xcd - r) * q) + tloc;
    int2 tk = tasks[task];
    int ge = tk.x, m0 = tk.y;
    int cntE = ecount[ge];
    int n0 = panel * BN;

    __shared__ __align__(16) char ldsA[3][8192];      // 128 rows x 32 cols bf16 (64B rows)
    __shared__ __align__(16) char ldsB[3][BN * 64];   // BN rows x 32 cols
    __shared__ int ents[128];

    int tid = threadIdx.x;
    if (tid < 128) {
        int rr = m0 + tid;
        if (rr >= cntE) rr = cntE - 1;         // clamp: duplicate, store-masked
        ents[tid] = elist[ge*N_TOK + rr];
    }
    __syncthreads();

    int lane = tid & 63, wv = tid >> 6;       // 4 waves
    int wm = wv >> 1, wn = wv & 1;            // 2x2 wave grid
    int lr = lane & 15, lg = lane >> 4;       // frag row / granule(8 bf16)
    int cr = lane >> 2;                       // row within 16-row staging chunk
    int csw = (lane & 3) ^ ((lane >> 3) & 3); // pre-swizzled source granule (key=(row>>1)&3)

    const char* sA1[2]; const char* sB1[BCH];
    const char* sA2[2]; const char* sB2[BCH];
    size_t rowB1 = (size_t)k1 * 2;
    #pragma unroll
    for (int j = 0; j < 2; ++j)
        sA1[j] = (const char*)A1 + (size_t)(ents[32*wv + 16*j + cr] >> shift1) * rowB1 + csw*16;
    #pragma unroll
    for (int j = 0; j < BCH; ++j)
        sB1[j] = (const char*)(B1 + (size_t)(ge*NDIM + n0 + (BN/4)*wv + 16*j + cr) * k1) + csw*16;
    int nk1 = k1 >> 5;
    int H = nk1;
    if constexpr (TWOPASS) {
        size_t rowB2 = (size_t)k2 * 2;
        #pragma unroll
        for (int j = 0; j < 2; ++j)
            sA2[j] = (const char*)A2 + (size_t)(ents[32*wv + 16*j + cr] >> shift2) * rowB2 + csw*16;
        #pragma unroll
        for (int j = 0; j < BCH; ++j)
            sB2[j] = (const char*)(B2 + (size_t)(ge*NDIM + n0 + (BN/4)*wv + 16*j + cr) * k2) + csw*16;
        H += (k2 >> 5);
    }

    auto stage = [&](int h) {
        int qb = h % 3;
        char* dA = ldsA[qb] + wv*2048;            // 32 rows x 64B
        char* dB = ldsB[qb] + wv*(BN*16);         // BN/4 rows x 64B
        if (!TWOPASS || h < nk1) {
            size_t off = (size_t)h << 6;          // 32 cols * 2B per step
            gld_lds16(sA1[0] + off, dA);
            gld_lds16(sA1[1] + off, dA + 1024);
            #pragma unroll
            for (int j = 0; j < BCH; ++j) gld_lds16(sB1[j] + off, dB + j*1024);
        } else {
            size_t off = (size_t)(h - nk1) << 6;
            gld_lds16(sA2[0] + off, dA);
            gld_lds16(sA2[1] + off, dA + 1024);
            #pragma unroll
            for (int j = 0; j < BCH; ++j) gld_lds16(sB2[j] + off, dB + j*1024);
        }
    };

    f32x4 acc[4][NFR] = {};

    stage(0);
    stage(1);
    if constexpr (BN == 256) asm volatile("s_waitcnt vmcnt(6)" ::: "memory");
    else                     asm volatile("s_waitcnt vmcnt(4)" ::: "memory");
    __builtin_amdgcn_s_barrier();

    #pragma unroll 1
    for (int s = 0; s < H; ++s) {
        if (s + 2 < H) stage(s + 2);                   // into buf (s+2)%3

        const char* bA = ldsA[s % 3];
        const char* bB = ldsB[s % 3];
        bf16x8 av[4], bv[NFR];
        #pragma unroll
        for (int mi = 0; mi < 4; ++mi) {
            int ar = wm*64 + mi*16 + lr;
            av[mi] = *(const bf16x8*)(bA + ar*64 + ((lg ^ ((ar >> 1) & 3)) << 4));
        }
        #pragma unroll
        for (int ni = 0; ni < NFR; ++ni) {
            int br_ = wn*(BN/2) + ni*16 + lr;
            bv[ni] = *(const bf16x8*)(bB + br_*64 + ((lg ^ ((br_ >> 1) & 3)) << 4));
        }
        #pragma unroll
        for (int mi = 0; mi < 4; ++mi)
            #pragma unroll
            for (int ni = 0; ni < NFR; ++ni)
                acc[mi][ni] = __builtin_amdgcn_mfma_f32_16x16x32_bf16(
                    av[mi], bv[ni], acc[mi][ni], 0, 0, 0);

        if (s + 2 < H) {
            if constexpr (BN == 256) asm volatile("s_waitcnt vmcnt(6)" ::: "memory");
            else                     asm volatile("s_waitcnt vmcnt(4)" ::: "memory");
        } else {
            asm volatile("s_waitcnt vmcnt(0)" ::: "memory");
        }
        __builtin_amdgcn_s_barrier();
    }

    // epilogue: bias (+bias2), optional relu, bf16 scatter to Out[entry][col]
    #pragma unroll
    for (int ni = 0; ni < NFR; ++ni) {
        int col = n0 + wn*(BN/2) + ni*16 + lr;
        float b = bias1[(size_t)ge*NDIM + col];
        if constexpr (TWOPASS) b += bias2[(size_t)ge*NDIM + col];
        #pragma unroll
        for (int mi = 0; mi < 4; ++mi) {
            #pragma unroll
            for (int j = 0; j < 4; ++j) {
                int rloc = wm*64 + mi*16 + lg*4 + j;
                if (m0 + rloc < cntE) {
                    float v = acc[mi][ni][j] + b;
                    if constexpr (RELU) v = fmaxf(v, 0.f);
                    Out[(size_t)ents[rloc] * NDIM + col] = (__bf16)v;
                }
            }
        }
    }
}

// ---------------- combine: out[t] = w0*Y[2t] + w1*Y[2t+1] ----------------
__global__ void combine_k(const __bf16* __restrict__ Y, const float* __restrict__ wslot,
                          float* __restrict__ out) {
    int idx = blockIdx.x * blockDim.x + threadIdx.x;
    int t = idx >> 6;
    int o = (idx & 63) * 8;
    bf16x8 y0 = *(const bf16x8*)(Y + (size_t)(2*t)   * ODIM + o);
    bf16x8 y1 = *(const bf16x8*)(Y + (size_t)(2*t+1) * ODIM + o);
    float w0 = wslot[2*t], w1 = wslot[2*t+1];
    float4 r0, r1;
    r0.x = w0*(float)y0[0] + w1*(float)y1[0];
    r0.y = w0*(float)y0[1] + w1*(float)y1[1];
    r0.z = w0*(float)y0[2] + w1*(float)y1[2];
    r0.w = w0*(float)y0[3] + w1*(float)y1[3];
    r1.x = w0*(float)y0[4] + w1*(float)y1[4];
    r1.y = w0*(float)y0[5] + w1*(float)y1[5];
    r1.z = w0*(float)y0[6] + w1*(float)y1[6];
    r1.w = w0*(float)y0[7] + w1*(float)y1[7];
    float* op = out + (size_t)t * ODIM + o;
    ((float4*)op)[0] = r0;
    ((float4*)op)[1] = r1;
}

extern "C" void kernel_launch(void* const* d_in, const int* in_sizes, int n_in,
                              void* d_out, int out_size, void* d_ws, size_t ws_size,
                              hipStream_t stream) {
    const float* x  = (const float*)d_in[0];
    const float* Wm = (const float*)d_in[1];
    const float* bm = (const float*)d_in[2];
    const float* Wr = (const float*)d_in[3];
    const float* br = (const float*)d_in[4];
    const float* W1 = (const float*)d_in[5];
    const float* b1 = (const float*)d_in[6];
    const float* W2 = (const float*)d_in[7];
    const float* b2 = (const float*)d_in[8];
    const float* Wp = (const float*)d_in[9];
    const float* bp = (const float*)d_in[10];
    const float* W3 = (const float*)d_in[11];
    const float* b3 = (const float*)d_in[12];

    if (ws_size < WS_NEED) return;

    char* ws = (char*)d_ws;
    float* outp = (float*)d_out;

    float* pmsum  = (float*)ws;
    float* psum   = (float*)ws + 4;
    int*   cnt    = (int*)ws + 16;
    int*   ecount = (int*)ws + 20;
    int*   ntasks = (int*)ws + 34;
    float* wslot  = (float*)(ws + OFF_WSLOT);
    int*   elist  = (int*)(ws + OFF_ELIST);
    int2*  tasks  = (int2*)(ws + OFF_TASK);
    __bf16* xbf = (__bf16*)(ws + OFF_XBF);
    __bf16* w1b = (__bf16*)(ws + OFF_W1);
    __bf16* w2b = (__bf16*)(ws + OFF_W2);
    __bf16* wpb = (__bf16*)(ws + OFF_WP);
    __bf16* w3b = (__bf16*)(ws + OFF_W3);
    __bf16* H1  = (__bf16*)(ws + OFF_H1);
    __bf16* U   = (__bf16*)(ws + OFF_U);
    __bf16* Y   = (__bf16*)(ws + OFF_Y);

    hipMemsetAsync(d_ws, 0, 512, stream);

    prep_k<<<4352, 256, 0, stream>>>(x, Wm, bm, Wr, br, W1, W2, Wp, W3,
                                     xbf, w1b, w2b, wpb, w3b,
                                     pmsum, psum, cnt, ecount, elist, wslot);

    finalize_aux_k<<<1, 64, 0, stream>>>(pmsum, psum, cnt, ecount, tasks, ntasks,
                                         outp + (size_t)N_TOK*ODIM);

    expert_gemm_k<HDIM, 128, true, false><<<TASK_CAP*(HDIM/128), 256, 0, stream>>>(
        xbf, 1, DDIM, w1b, nullptr, 0, 0, nullptr, b1, nullptr, H1,
        ecount, elist, tasks, ntasks);

    expert_gemm_k<HDIM, 256, true, true><<<TASK_CAP*(HDIM/256), 256, 0, stream>>>(
        H1, 0, HDIM, w2b, xbf, 1, DDIM, wpb, b2, bp, U,
        ecount, elist, tasks, ntasks);

    expert_gemm_k<ODIM, 128, false, false><<<TASK_CAP*(ODIM/128), 256, 0, stream>>>(
        U, 0, HDIM, w3b, nullptr, 0, 0, nullptr, b3, nullptr, Y,
        ecount, elist, tasks, ntasks);

    combine_k<<<4096, 256, 0, stream>>>(Y, wslot, outp);
}

// Round 18
// 391.339 us; speedup vs baseline: 1.3214x; 1.3214x over previous
//
#include <hip/hip_runtime.h>
#include <hip/hip_bf16.h>

#define N_TOK 16384
#define DDIM  512
#define HDIM  1024
#define ODIM  512
#define NG    3
#define NE    4
#define NGE   12
#define TASK_CAP 272

typedef __bf16 bf16x8 __attribute__((ext_vector_type(8)));
typedef float  f32x4  __attribute__((ext_vector_type(4)));
typedef unsigned int u32;

// async global->LDS, 16B per lane, lane l lands at ldst + l*16 (wave-uniform dest)
__device__ __forceinline__ void gld_lds16(const void* gsrc, void* ldst) {
    __builtin_amdgcn_global_load_lds(
        (const __attribute__((address_space(1))) u32*)gsrc,
        (__attribute__((address_space(3))) u32*)ldst, 16, 0, 0);
}

// ---------------- workspace layout (bytes) ----------------
static constexpr size_t OFF_WSLOT = 512;                               // N*2 floats
static constexpr size_t OFF_ELIST = OFF_WSLOT + (size_t)N_TOK*2*4;     // 12*N ints
static constexpr size_t OFF_TASK  = 917504;                            // int2[TASK_CAP]
static constexpr size_t OFF_XBF   = 1048576;                           // N*D bf16
static constexpr size_t OFF_W1    = OFF_XBF + (size_t)N_TOK*DDIM*2;
static constexpr size_t OFF_W2    = OFF_W1  + (size_t)NGE*HDIM*DDIM*2;
static constexpr size_t OFF_WP    = OFF_W2  + (size_t)NGE*HDIM*HDIM*2;
static constexpr size_t OFF_W3    = OFF_WP  + (size_t)NGE*HDIM*DDIM*2;
static constexpr size_t OFF_H1    = OFF_W3  + (size_t)NGE*ODIM*HDIM*2;
static constexpr size_t OFF_U     = OFF_H1  + (size_t)N_TOK*2*HDIM*2;
static constexpr size_t OFF_Y     = OFF_U   + (size_t)N_TOK*2*HDIM*2;
static constexpr size_t WS_NEED   = OFF_Y   + (size_t)N_TOK*2*ODIM*2;

// ---------------- fused prep: blocks [0,256) route, rest cast fp32->bf16 ----------------
__global__ __launch_bounds__(256) void prep_k(
        const float* __restrict__ x,  const float* __restrict__ Wm,
        const float* __restrict__ bm, const float* __restrict__ Wr,
        const float* __restrict__ br,
        const float* __restrict__ w1, const float* __restrict__ w2,
        const float* __restrict__ wp, const float* __restrict__ w3,
        __bf16* xbf, __bf16* w1b, __bf16* w2b, __bf16* wpb, __bf16* w3b,
        float* pmsum, float* psum, int* cnt, int* ecount,
        int* elist, float* wslot) {
    __shared__ float lpm[NG];
    __shared__ float lpsum[NGE];
    __shared__ int   lcnt[NG];
    __shared__ int   lec[NGE];
    __shared__ int   lbase[NGE];
    __shared__ int   lentry[NGE][64];

    int tid = threadIdx.x;

    if (blockIdx.x >= 256) {
        // ---------- cast path ----------
        int cbid = blockIdx.x - 256;
        int ctid = cbid * 256 + tid;
        int stride = (gridDim.x - 256) * 256;
        auto seg = [&](const float* __restrict__ s, __bf16* __restrict__ d, int n4) {
            const float4* s4 = (const float4*)s;
            uint2* d4 = (uint2*)d;
            for (int i = ctid; i < n4; i += stride) {
                float4 v = s4[i];
                union { __bf16 h[4]; uint2 u; } o;
                o.h[0] = (__bf16)v.x; o.h[1] = (__bf16)v.y;
                o.h[2] = (__bf16)v.z; o.h[3] = (__bf16)v.w;
                d4[i] = o.u;
            }
        };
        seg(x,  xbf, N_TOK*DDIM/4);
        seg(w1, w1b, NGE*HDIM*DDIM/4);
        seg(w2, w2b, NGE*HDIM*HDIM/4);
        seg(wp, wpb, NGE*HDIM*DDIM/4);
        seg(w3, w3b, NGE*ODIM*HDIM/4);
        return;
    }

    // ---------- routing path (block-aggregated atomics) ----------
    if (tid < NG)  { lpm[tid] = 0.f; lcnt[tid] = 0; }
    if (tid < NGE) { lpsum[tid] = 0.f; lec[tid] = 0; }
    __syncthreads();

    int wid = tid >> 6, lane = tid & 63;

    #pragma unroll 1
    for (int i = 0; i < 16; ++i) {
        int t = blockIdx.x * 64 + i * 4 + wid;

        const float4* xr = (const float4*)(x + (size_t)t * DDIM);
        float4 xa = xr[lane*2], xb = xr[lane*2+1];

        float meta[NG];
        #pragma unroll
        for (int gi = 0; gi < NG; ++gi) {
            const float4* w = (const float4*)(Wm + gi*DDIM);
            float4 wa = w[lane*2], wb = w[lane*2+1];
            float s = xa.x*wa.x + xa.y*wa.y + xa.z*wa.z + xa.w*wa.w
                    + xb.x*wb.x + xb.y*wb.y + xb.z*wb.z + xb.w*wb.w;
            #pragma unroll
            for (int off = 32; off > 0; off >>= 1) s += __shfl_xor(s, off);
            meta[gi] = s + bm[gi];
        }
        int g = 0;
        if (meta[1] > meta[g]) g = 1;
        if (meta[2] > meta[g]) g = 2;

        float mm = fmaxf(meta[0], fmaxf(meta[1], meta[2]));
        float e0 = expf(meta[0]-mm), e1 = expf(meta[1]-mm), e2 = expf(meta[2]-mm);
        float inv = 1.f / (e0 + e1 + e2);

        float sel[NE];
        #pragma unroll
        for (int e = 0; e < NE; ++e) {
            const float4* w = (const float4*)(Wr + (size_t)(g*NE + e)*DDIM);
            float4 wa = w[lane*2], wb = w[lane*2+1];
            float s = xa.x*wa.x + xa.y*wa.y + xa.z*wa.z + xa.w*wa.w
                    + xb.x*wb.x + xb.y*wb.y + xb.z*wb.z + xb.w*wb.w;
            #pragma unroll
            for (int off = 32; off > 0; off >>= 1) s += __shfl_xor(s, off);
            sel[e] = s + br[g*NE + e];
        }
        float ms = fmaxf(fmaxf(sel[0],sel[1]), fmaxf(sel[2],sel[3]));
        float pe[NE]; float ss = 0.f;
        #pragma unroll
        for (int e = 0; e < NE; ++e) { pe[e] = expf(sel[e]-ms); ss += pe[e]; }
        float invs = 1.f / ss;

        int i0 = 0;
        #pragma unroll
        for (int e = 1; e < NE; ++e) if (sel[e] > sel[i0]) i0 = e;
        int i1 = (i0 == 0) ? 1 : 0;
        #pragma unroll
        for (int e = 0; e < NE; ++e) if (e != i0 && sel[e] > sel[i1]) i1 = e;
        float ew = expf(sel[i1] - sel[i0]);
        float wden = 1.f / (1.f + ew);

        if (lane == 0) {
            atomicAdd(&lpm[0], e0*inv);
            atomicAdd(&lpm[1], e1*inv);
            atomicAdd(&lpm[2], e2*inv);
            #pragma unroll
            for (int e = 0; e < NE; ++e) atomicAdd(&lpsum[g*NE + e], pe[e]*invs);
            atomicAdd(&lcnt[g], 1);
            int ee0 = g*NE + i0, ee1 = g*NE + i1;
            int p0 = atomicAdd(&lec[ee0], 1);
            lentry[ee0][p0] = t*2;
            int p1 = atomicAdd(&lec[ee1], 1);
            lentry[ee1][p1] = t*2 + 1;
            wslot[t*2]   = wden;
            wslot[t*2+1] = ew * wden;
        }
    }
    __syncthreads();

    if (tid < NG)  { atomicAdd(pmsum + tid, lpm[tid]); atomicAdd(cnt + tid, lcnt[tid]); }
    if (tid < NGE) { atomicAdd(psum + tid, lpsum[tid]);
                     lbase[tid] = atomicAdd(ecount + tid, lec[tid]); }
    __syncthreads();

    for (int e = wid; e < NGE; e += 4) {
        int c = lec[e], base = lbase[e];
        for (int j = lane; j < c; j += 64)
            elist[e*N_TOK + base + j] = lentry[e][j];
    }
}

// ---------------- aux scalar + GEMM task list (BM=128 tiles) ----------------
__global__ void finalize_aux_k(const float* pmsum, const float* psum, const int* cnt,
                               const int* ecount, int2* tasks, int* ntasks,
                               float* outAux) {
    if (threadIdx.x != 0 || blockIdx.x != 0) return;
    float s = 0.f;
    for (int i = 0; i < NG; ++i) { float p = pmsum[i] / (float)N_TOK; s += p*p; }
    float aux = 0.01f * NG * s;
    for (int gg = 0; gg < NG; ++gg) {
        int c = cnt[gg];
        if (c > 0) {
            float s2 = 0.f;
            for (int e = 0; e < NE; ++e) { float m = psum[gg*NE+e] / (float)c; s2 += m*m; }
            aux += 0.01f * NE * s2;
        }
    }
    *outAux = aux;
    int nt = 0;
    for (int ge = 0; ge < NGE; ++ge) {
        int c = ecount[ge];
        for (int m0 = 0; m0 < c; m0 += 128) tasks[nt++] = make_int2(ge, m0);
    }
    *ntasks = nt;
}

// ---------------- grouped GEMM: 128x128, BK=32 triple-buffer, counted vmcnt ----------
// Best-known (r12/r14/r16, 392us total): chunked-bijective task->XCD map
// (weights L2-resident per XCD), 3 blocks/CU, depth-2 prefetch, counted
// vmcnt(4), one s_barrier per step, bf16 store to Out.
template<int NDIM, bool RELU, bool TWOPASS>
__global__ __launch_bounds__(256) void expert_gemm_k(
        const __bf16* __restrict__ A1, int shift1, int k1, const __bf16* __restrict__ B1,
        const __bf16* __restrict__ A2, int shift2, int k2, const __bf16* __restrict__ B2,
        const float* __restrict__ bias1, const float* __restrict__ bias2,
        __bf16* __restrict__ Out,
        const int* __restrict__ ecount, const int* __restrict__ elist,
        const int2* __restrict__ tasks, const int* __restrict__ ntasks) {
    constexpr int NPAN = NDIM / 128;            // 8 or 4 (power of two)
    constexpr int PSH  = (NPAN == 8) ? 3 : 2;
    int T = *ntasks;
    int q = T >> 3, r = T & 7;
    int xcd  = blockIdx.x & 7;
    int idx  = blockIdx.x >> 3;                 // local block index on this XCD
    int tloc = idx >> PSH;                      // local task
    int panel = idx & (NPAN - 1);
    int cx = q + (xcd < r ? 1 : 0);
    if (tloc >= cx) return;
    int task = (xcd < r ? xcd * (q + 1) : r * (q + 1) + (xcd - r) * q) + tloc;
    int2 tk = tasks[task];
    int ge = tk.x, m0 = tk.y;
    int cntE = ecount[ge];
    int n0 = panel * 128;

    __shared__ __align__(16) char ldsA[3][8192];    // buf: 128 rows x 32 cols bf16 (64B rows)
    __shared__ __align__(16) char ldsB[3][8192];
    __shared__ int ents[128];

    int tid = threadIdx.x;
    if (tid < 128) {
        int rr = m0 + tid;
        if (rr >= cntE) rr = cntE - 1;         // clamp: duplicate, store-masked
        ents[tid] = elist[ge*N_TOK + rr];
    }
    __syncthreads();

    int lane = tid & 63, wv = tid >> 6;       // 4 waves
    int wm = wv >> 1, wn = wv & 1;            // 2x2 wave grid
    int lr = lane & 15, lg = lane >> 4;       // frag row / granule(8 bf16)
    int cr = lane >> 2;                       // row within 16-row staging chunk
    int csw = (lane & 3) ^ ((lane >> 3) & 3); // pre-swizzled source granule (key=(row>>1)&3)

    const char* sA1[2]; const char* sB1[2];
    const char* sA2[2]; const char* sB2[2];
    size_t rowB1 = (size_t)k1 * 2;
    #pragma unroll
    for (int j = 0; j < 2; ++j) {
        sA1[j] = (const char*)A1 + (size_t)(ents[32*wv + 16*j + cr] >> shift1) * rowB1 + csw*16;
        sB1[j] = (const char*)(B1 + (size_t)(ge*NDIM + n0 + 32*wv + 16*j + cr) * k1) + csw*16;
    }
    int nk1 = k1 >> 5;
    int H = nk1;
    if constexpr (TWOPASS) {
        size_t rowB2 = (size_t)k2 * 2;
        #pragma unroll
        for (int j = 0; j < 2; ++j) {
            sA2[j] = (const char*)A2 + (size_t)(ents[32*wv + 16*j + cr] >> shift2) * rowB2 + csw*16;
            sB2[j] = (const char*)(B2 + (size_t)(ge*NDIM + n0 + 32*wv + 16*j + cr) * k2) + csw*16;
        }
        H += (k2 >> 5);
    }

    auto stage = [&](int h) {
        int qb = h % 3;
        char* dA = ldsA[qb] + wv*2048;        // 32 rows x 64B
        char* dB = ldsB[qb] + wv*2048;
        if (!TWOPASS || h < nk1) {
            size_t off = (size_t)h << 6;      // 32 cols * 2B per step
            gld_lds16(sA1[0] + off, dA);
            gld_lds16(sA1[1] + off, dA + 1024);
            gld_lds16(sB1[0] + off, dB);
            gld_lds16(sB1[1] + off, dB + 1024);
        } else {
            size_t off = (size_t)(h - nk1) << 6;
            gld_lds16(sA2[0] + off, dA);
            gld_lds16(sA2[1] + off, dA + 1024);
            gld_lds16(sB2[0] + off, dB);
            gld_lds16(sB2[1] + off, dB + 1024);
        }
    };

    f32x4 acc[4][4] = {};

    stage(0);
    stage(1);
    asm volatile("s_waitcnt vmcnt(4)" ::: "memory");   // buf0 landed; buf1 flying
    __builtin_amdgcn_s_barrier();

    #pragma unroll 1
    for (int s = 0; s < H; ++s) {
        if (s + 2 < H) stage(s + 2);                   // into buf (s+2)%3

        const char* bA = ldsA[s % 3];
        const char* bB = ldsB[s % 3];
        bf16x8 av[4], bv[4];
        #pragma unroll
        for (int mi = 0; mi < 4; ++mi) {
            int ar = wm*64 + mi*16 + lr;
            av[mi] = *(const bf16x8*)(bA + ar*64 + ((lg ^ ((ar >> 1) & 3)) << 4));
        }
        #pragma unroll
        for (int ni = 0; ni < 4; ++ni) {
            int br_ = wn*64 + ni*16 + lr;
            bv[ni] = *(const bf16x8*)(bB + br_*64 + ((lg ^ ((br_ >> 1) & 3)) << 4));
        }
        #pragma unroll
        for (int mi = 0; mi < 4; ++mi)
            #pragma unroll
            for (int ni = 0; ni < 4; ++ni)
                acc[mi][ni] = __builtin_amdgcn_mfma_f32_16x16x32_bf16(
                    av[mi], bv[ni], acc[mi][ni], 0, 0, 0);

        if (s + 2 < H)      asm volatile("s_waitcnt vmcnt(4)" ::: "memory");
        else                asm volatile("s_waitcnt vmcnt(0)" ::: "memory");
        __builtin_amdgcn_s_barrier();
    }

    // epilogue: bias (+bias2), optional relu, bf16 scatter to Out[entry][col]
    #pragma unroll
    for (int ni = 0; ni < 4; ++ni) {
        int col = n0 + wn*64 + ni*16 + lr;
        float b = bias1[(size_t)ge*NDIM + col];
        if constexpr (TWOPASS) b += bias2[(size_t)ge*NDIM + col];
        #pragma unroll
        for (int mi = 0; mi < 4; ++mi) {
            #pragma unroll
            for (int j = 0; j < 4; ++j) {
                int rloc = wm*64 + mi*16 + lg*4 + j;
                if (m0 + rloc < cntE) {
                    float v = acc[mi][ni][j] + b;
                    if constexpr (RELU) v = fmaxf(v, 0.f);
                    Out[(size_t)ents[rloc] * NDIM + col] = (__bf16)v;
                }
            }
        }
    }
}

// ---------------- combine: out[t] = w0*Y[2t] + w1*Y[2t+1] ----------------
__global__ void combine_k(const __bf16* __restrict__ Y, const float* __restrict__ wslot,
                          float* __restrict__ out) {
    int idx = blockIdx.x * blockDim.x + threadIdx.x;
    int t = idx >> 6;
    int o = (idx & 63) * 8;
    bf16x8 y0 = *(const bf16x8*)(Y + (size_t)(2*t)   * ODIM + o);
    bf16x8 y1 = *(const bf16x8*)(Y + (size_t)(2*t+1) * ODIM + o);
    float w0 = wslot[2*t], w1 = wslot[2*t+1];
    float4 r0, r1;
    r0.x = w0*(float)y0[0] + w1*(float)y1[0];
    r0.y = w0*(float)y0[1] + w1*(float)y1[1];
    r0.z = w0*(float)y0[2] + w1*(float)y1[2];
    r0.w = w0*(float)y0[3] + w1*(float)y1[3];
    r1.x = w0*(float)y0[4] + w1*(float)y1[4];
    r1.y = w0*(float)y0[5] + w1*(float)y1[5];
    r1.z = w0*(float)y0[6] + w1*(float)y1[6];
    r1.w = w0*(float)y0[7] + w1*(float)y1[7];
    float* op = out + (size_t)t * ODIM + o;
    ((float4*)op)[0] = r0;
    ((float4*)op)[1] = r1;
}

extern "C" void kernel_launch(void* const* d_in, const int* in_sizes, int n_in,
                              void* d_out, int out_size, void* d_ws, size_t ws_size,
                              hipStream_t stream) {
    const float* x  = (const float*)d_in[0];
    const float* Wm = (const float*)d_in[1];
    const float* bm = (const float*)d_in[2];
    const float* Wr = (const float*)d_in[3];
    const float* br = (const float*)d_in[4];
    const float* W1 = (const float*)d_in[5];
    const float* b1 = (const float*)d_in[6];
    const float* W2 = (const float*)d_in[7];
    const float* b2 = (const float*)d_in[8];
    const float* Wp = (const float*)d_in[9];
    const float* bp = (const float*)d_in[10];
    const float* W3 = (const float*)d_in[11];
    const float* b3 = (const float*)d_in[12];

    if (ws_size < WS_NEED) return;

    char* ws = (char*)d_ws;
    float* outp = (float*)d_out;

    float* pmsum  = (float*)ws;
    float* psum   = (float*)ws + 4;
    int*   cnt    = (int*)ws + 16;
    int*   ecount = (int*)ws + 20;
    int*   ntasks = (int*)ws + 34;
    float* wslot  = (float*)(ws + OFF_WSLOT);
    int*   elist  = (int*)(ws + OFF_ELIST);
    int2*  tasks  = (int2*)(ws + OFF_TASK);
    __bf16* xbf = (__bf16*)(ws + OFF_XBF);
    __bf16* w1b = (__bf16*)(ws + OFF_W1);
    __bf16* w2b = (__bf16*)(ws + OFF_W2);
    __bf16* wpb = (__bf16*)(ws + OFF_WP);
    __bf16* w3b = (__bf16*)(ws + OFF_W3);
    __bf16* H1  = (__bf16*)(ws + OFF_H1);
    __bf16* U   = (__bf16*)(ws + OFF_U);
    __bf16* Y   = (__bf16*)(ws + OFF_Y);

    hipMemsetAsync(d_ws, 0, 512, stream);

    prep_k<<<4352, 256, 0, stream>>>(x, Wm, bm, Wr, br, W1, W2, Wp, W3,
                                     xbf, w1b, w2b, wpb, w3b,
                                     pmsum, psum, cnt, ecount, elist, wslot);

    finalize_aux_k<<<1, 64, 0, stream>>>(pmsum, psum, cnt, ecount, tasks, ntasks,
                                         outp + (size_t)N_TOK*ODIM);

    expert_gemm_k<HDIM, true, false><<<TASK_CAP*(HDIM/128), 256, 0, stream>>>(
        xbf, 1, DDIM, w1b, nullptr, 0, 0, nullptr, b1, nullptr, H1,
        ecount, elist, tasks, ntasks);

    expert_gemm_k<HDIM, true, true><<<TASK_CAP*(HDIM/128), 256, 0, stream>>>(
        H1, 0, HDIM, w2b, xbf, 1, DDIM, wpb, b2, bp, U,
        ecount, elist, tasks, ntasks);

    expert_gemm_k<ODIM, false, false><<<TASK_CAP*(ODIM/128), 256, 0, stream>>>(
        U, 0, HDIM, w3b, nullptr, 0, 0, nullptr, b3, nullptr, Y,
        ecount, elist, tasks, ntasks);

    combine_k<<<4096, 256, 0, stream>>>(Y, wslot, outp);
}